// Round 1
// baseline (263.740 us; speedup 1.0000x reference)
//
#include <hip/hip_runtime.h>
#include <math.h>

#define NEGINF (-1e30f)

// Problem constants (fixed by setup_inputs)
#define T_DIM 1024
#define B_DIM 128
#define C_DIM 256
#define S_DIM 64
#define L_DIM (2 * S_DIM + 1)  // 129

// One block per batch element. 256 threads: thread tid < L owns extended
// state tid; all 256 threads stage the per-timestep class row into LDS.
__global__ __launch_bounds__(256) void ctc_alpha_kernel(
    const float* __restrict__ log_probs,   // (T, B, C)
    const int* __restrict__ targets,       // (B, S)
    const int* __restrict__ target_lengths,// (B,)
    float* __restrict__ per_batch)         // (B,) loss_b / len_b
{
    const int b = blockIdx.x;
    const int tid = threadIdx.x;

    __shared__ float rbuf[2][C_DIM];     // class-row double buffer
    __shared__ float abuf[2][L_DIM + 3]; // alpha double buffer (+pad)

    // Per-thread extended-label info (computed once).
    const bool active = (tid < L_DIM);
    int e = 0;        // extended label class for state tid (blank = 0)
    bool skip = false;
    if (active && (tid & 1)) {
        e = targets[b * S_DIM + (tid >> 1)];
        if (tid >= 3) {
            skip = (e != targets[b * S_DIM + (tid >> 1) - 1]);
        }
    }

    const float* base = log_probs + (size_t)b * C_DIM;
    const size_t stride = (size_t)B_DIM * C_DIM;  // floats per timestep

    // Prologue: rows 0 and 1, issue row 2.
    float r0 = base[tid];
    float r1 = base[stride + tid];
    rbuf[0][tid] = r0;
    __syncthreads();
    // t = 0 init phase: alpha0 lives in abuf[0]; stage row1 into rbuf[1].
    if (active) {
        abuf[0][tid] = (tid < 2) ? rbuf[0][e] : NEGINF;
    }
    rbuf[1][tid] = r1;
    float pre = base[2 * stride + tid];  // row 2 in flight
    __syncthreads();

    // Main recursion. Phase t: reads abuf[(t-1)&1] and rbuf[t&1],
    // writes abuf[t&1] and rbuf[(t+1)&1]. One barrier per step.
    for (int t = 1; t < T_DIM; ++t) {
        const float* aOld = abuf[(t - 1) & 1];
        float* aNew = abuf[t & 1];
        if (active) {
            float a0 = aOld[tid];
            float a1 = (tid >= 1) ? aOld[tid - 1] : NEGINF;
            float a2 = skip ? aOld[tid - 2] : NEGINF;
            float m = fmaxf(a0, fmaxf(a1, a2));
            float s = __expf(a0 - m) + __expf(a1 - m) +
                      (skip ? __expf(a2 - m) : 0.0f);
            aNew[tid] = m + __logf(s) + rbuf[t & 1][e];
        }
        rbuf[(t + 1) & 1][tid] = pre;  // stage row t+1
        if (t + 2 < T_DIM) {
            pre = base[(size_t)(t + 2) * stride + tid];  // issue row t+2
        }
        __syncthreads();
    }

    // Terminal: loss_b = -logaddexp(alpha[2*len], alpha[2*len-1])
    if (tid == 0) {
        const int len = target_lengths[b];
        const float* aF = abuf[(T_DIM - 1) & 1];
        float aLast = aF[2 * len];
        float aPrev = aF[2 * len - 1];
        float m = fmaxf(aLast, aPrev);
        float la = m + __logf(__expf(aLast - m) + __expf(aPrev - m));
        float loss = -la;
        // zero_infinity: keep iff finite and < 1e29, else 0
        if (!isfinite(loss) || !(loss < 1e29f)) loss = 0.0f;
        per_batch[b] = loss / (float)len;
    }
}

// Single-wave deterministic reduction: mean over B of per_batch.
__global__ __launch_bounds__(64) void ctc_reduce_kernel(
    const float* __restrict__ per_batch, float* __restrict__ out)
{
    const int lane = threadIdx.x;
    float v = per_batch[lane] + per_batch[lane + 64];
    #pragma unroll
    for (int off = 32; off > 0; off >>= 1) {
        v += __shfl_down(v, off, 64);
    }
    if (lane == 0) out[0] = v / (float)B_DIM;
}

extern "C" void kernel_launch(void* const* d_in, const int* in_sizes, int n_in,
                              void* d_out, int out_size, void* d_ws, size_t ws_size,
                              hipStream_t stream) {
    const float* log_probs = (const float*)d_in[0];
    const int* targets = (const int*)d_in[1];
    const int* target_lengths = (const int*)d_in[2];
    float* out = (float*)d_out;
    float* per_batch = (float*)d_ws;  // B_DIM floats of scratch

    ctc_alpha_kernel<<<B_DIM, 256, 0, stream>>>(log_probs, targets,
                                                target_lengths, per_batch);
    ctc_reduce_kernel<<<1, 64, 0, stream>>>(per_batch, out);
}

// Round 3
// 213.433 us; speedup vs baseline: 1.2357x; 1.2357x over previous
//
#include <hip/hip_runtime.h>
#include <math.h>

#define NEGINF (-1e30f)

// Problem constants (fixed by setup_inputs)
#define T_DIM 1024
#define B_DIM 128
#define C_DIM 256
#define S_DIM 64
#define L_DIM (2 * S_DIM + 1)  // 129
#define PF 8                   // prefetch depth (register ring)

// lane i <- lane i-1; lane 0 <- NEGINF. wave_shr:1 DPP (gfx9-lineage ctrl 0x138).
__device__ __forceinline__ float shfl_up1_neginf(float x) {
    int r = __builtin_amdgcn_update_dpp(__float_as_int(NEGINF),
                                        __float_as_int(x),
                                        0x138 /*WAVE_SHR1*/, 0xF, 0xF, false);
    return __int_as_float(r);
}

// One wave (64 lanes) per batch element. Lane l owns extended states
// s0=2l (blank), s1=2l+1 (label targets[b,l]); lane 63 additionally owns
// s2=128 (blank). Alpha lives entirely in registers; the only cross-lane
// dependency per step is alpha[2l-1] = neighbor's s1 -> one DPP move.
__global__ __launch_bounds__(64) void ctc_alpha_kernel(
    const float* __restrict__ log_probs,    // (T, B, C)
    const int* __restrict__ targets,        // (B, S)
    const int* __restrict__ target_lengths, // (B,)
    float* __restrict__ per_batch)          // (B,) loss_b / len_b
{
    const int b = blockIdx.x;
    const int lane = threadIdx.x;  // 0..63

    __shared__ float als[L_DIM + 3];

    // Per-lane fixed label class and skip flag (constant over t).
    const int e1 = targets[b * S_DIM + lane];               // class of state 2l+1
    const int ep = (lane > 0) ? targets[b * S_DIM + lane - 1] : 0;
    const bool skip = (lane > 0) && (e1 != ep);

    const float* base = log_probs + (size_t)b * C_DIM;
    const size_t stride = (size_t)B_DIM * C_DIM;  // floats per timestep

    // t = 0 init.
    float a0, a1, a2;
    {
        float r00 = base[0];        // lp[0,b,blank]
        float r0e = base[e1];       // lp[0,b,e1]
        a0 = (lane == 0) ? r00 : NEGINF;  // alpha[0]
        a1 = (lane == 0) ? r0e : NEGINF;  // alpha[1]
        a2 = NEGINF;                      // alpha[128]
    }

    // Prefetch ring: slot k holds lp values for timestep t with (t-1)&7 == k.
    float pb[PF], pl[PF];
    #pragma unroll
    for (int k = 0; k < PF; ++k) {
        const size_t off = (size_t)(1 + k) * stride;
        pb[k] = base[off];       // blank prob
        pl[k] = base[off + e1];  // label prob
    }

    // One recursion step given this timestep's blank/label log-probs.
    #define CTC_STEP(LPB, LPL)                                               \
    do {                                                                     \
        float am1 = shfl_up1_neginf(a1);             /* alpha[2l-1] */       \
        /* even blank state s=2l: LSE(a0, am1) + lpb */                      \
        float m0 = fmaxf(a0, am1);                                           \
        float n0 = m0 + __logf(__expf(a0 - m0) + __expf(am1 - m0)) + (LPB);  \
        /* odd label state s=2l+1: LSE(a1, a0, skip?am1) + lpl */            \
        float s2v = skip ? am1 : NEGINF;                                     \
        float m1 = fmaxf(fmaxf(a1, a0), s2v);                                \
        float n1 = m1 + __logf(__expf(a1 - m1) + __expf(a0 - m1) +           \
                               __expf(s2v - m1)) + (LPL);                    \
        /* lane 63's extra state s=128: LSE(a2, a1) + lpb */                 \
        float m2 = fmaxf(a2, a1);                                            \
        float n2 = m2 + __logf(__expf(a2 - m2) + __expf(a1 - m2)) + (LPB);   \
        a0 = n0; a1 = n1; a2 = n2;                                           \
    } while (0)

    // Main loop: t = 1 .. 1016 in blocks of PF, prefetching t+PF.
    for (int tb = 1; tb + PF <= T_DIM; tb += PF) {
        #pragma unroll
        for (int k = 0; k < PF; ++k) {
            const int t = tb + k;
            CTC_STEP(pb[k], pl[k]);
            if (t + PF < T_DIM) {
                const size_t off = (size_t)(t + PF) * stride;
                pb[k] = base[off];
                pl[k] = base[off + e1];
            }
        }
    }
    // Tail: t = 1017 .. 1023 (slots 0..6).
    #pragma unroll
    for (int k = 0; k < PF - 1; ++k) {
        CTC_STEP(pb[k], pl[k]);
    }
    #undef CTC_STEP

    // Publish final alpha and compute the per-batch loss.
    als[2 * lane] = a0;
    als[2 * lane + 1] = a1;
    if (lane == 63) als[L_DIM - 1] = a2;
    __syncthreads();

    if (lane == 0) {
        const int len = target_lengths[b];
        float aLast = als[2 * len];
        float aPrev = als[2 * len - 1];
        float m = fmaxf(aLast, aPrev);
        float la = m + __logf(__expf(aLast - m) + __expf(aPrev - m));
        float loss = -la;
        if (!isfinite(loss) || !(loss < 1e29f)) loss = 0.0f;
        per_batch[b] = loss / (float)len;
    }
}

// Single-wave deterministic reduction: mean over B of per_batch.
__global__ __launch_bounds__(64) void ctc_reduce_kernel(
    const float* __restrict__ per_batch, float* __restrict__ out)
{
    const int lane = threadIdx.x;
    float v = per_batch[lane] + per_batch[lane + 64];
    #pragma unroll
    for (int off = 32; off > 0; off >>= 1) {
        v += __shfl_down(v, off, 64);
    }
    if (lane == 0) out[0] = v / (float)B_DIM;
}

extern "C" void kernel_launch(void* const* d_in, const int* in_sizes, int n_in,
                              void* d_out, int out_size, void* d_ws, size_t ws_size,
                              hipStream_t stream) {
    const float* log_probs = (const float*)d_in[0];
    const int* targets = (const int*)d_in[1];
    const int* target_lengths = (const int*)d_in[2];
    float* out = (float*)d_out;
    float* per_batch = (float*)d_ws;  // B_DIM floats of scratch

    ctc_alpha_kernel<<<B_DIM, 64, 0, stream>>>(log_probs, targets,
                                               target_lengths, per_batch);
    ctc_reduce_kernel<<<1, 64, 0, stream>>>(per_batch, out);
}

// Round 6
// 118.797 us; speedup vs baseline: 2.2201x; 1.7966x over previous
//
#include <hip/hip_runtime.h>
#include <math.h>

#define NEGINF (-1e30f)
#define LOG2E  1.4426950408889634f
#define LN2    0.6931471805599453f

// Problem constants (fixed by setup_inputs)
#define T_DIM 1024
#define B_DIM 128
#define C_DIM 256
#define S_DIM 64
#define L_DIM (2 * S_DIM + 1)  // 129
#define PF 32                  // prefetch depth; must divide T_DIM

// lane i <- lane i-1; lane 0 <- NEGINF. wave_shr:1 DPP (gfx9 ctrl 0x138).
__device__ __forceinline__ float shfl_up1_neginf(float x) {
    int r = __builtin_amdgcn_update_dpp(__float_as_int(NEGINF),
                                        __float_as_int(x),
                                        0x138 /*WAVE_SHR1*/, 0xF, 0xF, false);
    return __int_as_float(r);
}

// Native 2^x / log2(x) (v_exp_f32 / v_log_f32).
__device__ __forceinline__ float fexp2(float x) { return __builtin_amdgcn_exp2f(x); }
__device__ __forceinline__ float flog2(float x) { return __builtin_amdgcn_logf(x); }

// Opaque divergent zero: defeats uniformity analysis so the blank-prob load
// stays a VECTOR load (global_load_dword, in-order vmcnt) instead of being
// scalarized to s_load_dword (out-of-order lgkmcnt -> lgkmcnt(0) per use,
// which serialized the whole prefetch ring in round 2).
__device__ __forceinline__ int opaque_zero() {
    int z;
    asm volatile("v_mov_b32 %0, 0" : "=v"(z));
    return z;
}

// One wave (64 lanes) per batch element. Lane l owns extended states
// s0=2l (blank), s1=2l+1 (label targets[b,l]); lane 63's a2 is state 128.
// Alpha lives in registers (log2 domain); cross-lane dep = one DPP per step.
__global__ __launch_bounds__(64) void ctc_alpha_kernel(
    const float* __restrict__ log_probs,    // (T, B, C)
    const int* __restrict__ targets,        // (B, S)
    const int* __restrict__ target_lengths, // (B,)
    float* __restrict__ per_batch)          // (B,) loss_b / len_b
{
    const int b = blockIdx.x;
    const int lane = threadIdx.x;  // 0..63

    __shared__ float als[L_DIM + 3];

    // Per-lane fixed label class and skip flag (constant over t).
    const int e1 = targets[b * S_DIM + lane];               // class of state 2l+1
    const int ep = (lane > 0) ? targets[b * S_DIM + lane - 1] : 0;
    const bool skip = (lane > 0) && (e1 != ep);

    const int vz = opaque_zero();

    const float* base = log_probs + (size_t)b * C_DIM;
    const size_t stride = (size_t)B_DIM * C_DIM;  // floats per timestep

    // t = 0 init (log2 domain).
    float a0, a1, a2;
    {
        float r00 = base[vz];       // lp[0,b,blank] (vector load)
        float r0e = base[e1];       // lp[0,b,e1]
        a0 = (lane == 0) ? r00 * LOG2E : NEGINF;  // alpha[0]
        a1 = (lane == 0) ? r0e * LOG2E : NEGINF;  // alpha[1]
        a2 = NEGINF;                              // alpha[128]
    }

    // Prefetch ring: slot k holds raw lp for timestep t with (t-1)%PF == k.
    float pb[PF], pl[PF];
    #pragma unroll
    for (int k = 0; k < PF; ++k) {
        const float* p = base + (size_t)(1 + k) * stride;
        pb[k] = p[vz];       // blank prob (vector load)
        pl[k] = p[e1];       // label prob (gather)
    }

    // One recursion step (log2 domain); LPB/LPL are raw log-probs, scaled
    // here (the muls run parallel to the exp/log chain, not on it).
    #define CTC_STEP(LPB, LPL)                                                \
    do {                                                                      \
        float lpb = (LPB) * LOG2E;                                            \
        float lpl = (LPL) * LOG2E;                                            \
        float am1 = shfl_up1_neginf(a1);              /* alpha[2l-1] */       \
        float m0 = fmaxf(a0, am1);                                            \
        float n0 = m0 + flog2(fexp2(a0 - m0) + fexp2(am1 - m0)) + lpb;        \
        float s2v = skip ? am1 : NEGINF;                                      \
        float m1 = fmaxf(fmaxf(a1, a0), s2v);                                 \
        float n1 = m1 + flog2(fexp2(a1 - m1) + fexp2(a0 - m1) +               \
                              fexp2(s2v - m1)) + lpl;                         \
        float m2 = fmaxf(a2, a1);                                             \
        float n2 = m2 + flog2(fexp2(a2 - m2) + fexp2(a1 - m2)) + lpb;         \
        a0 = n0; a1 = n1; a2 = n2;                                            \
    } while (0)

    // Main loop: consume slot k (timestep tb+k), refill for tb+k+PF.
    // Prefetch timestep is clamped (uniform s_cselect, no branch); the
    // clamped duplicate loads land in slots the tail never consumes.
    for (int tb = 1; tb + PF <= T_DIM; tb += PF) {
        #pragma unroll
        for (int k = 0; k < PF; ++k) {
            CTC_STEP(pb[k], pl[k]);
            int tn = tb + k + PF;
            tn = (tn < T_DIM) ? tn : (T_DIM - 1);
            const float* p = base + (size_t)tn * stride;
            pb[k] = p[vz];
            pl[k] = p[e1];
        }
    }
    // Tail: remaining PF-1 steps (T_DIM % PF == 0 guarantees this count).
    #pragma unroll
    for (int k = 0; k < PF - 1; ++k) {
        CTC_STEP(pb[k], pl[k]);
    }
    #undef CTC_STEP

    // Publish final alpha (log2 domain) and compute per-batch loss.
    als[2 * lane] = a0;
    als[2 * lane + 1] = a1;
    if (lane == 63) als[L_DIM - 1] = a2;
    __syncthreads();

    if (lane == 0) {
        const int len = target_lengths[b];
        float aLast = als[2 * len];
        float aPrev = als[2 * len - 1];
        float m = fmaxf(aLast, aPrev);
        float la2 = m + flog2(fexp2(aLast - m) + fexp2(aPrev - m));
        float loss = -(la2 * LN2);
        if (!isfinite(loss) || !(loss < 1e29f)) loss = 0.0f;
        per_batch[b] = loss / (float)len;
    }
}

// Single-wave deterministic reduction: mean over B of per_batch.
__global__ __launch_bounds__(64) void ctc_reduce_kernel(
    const float* __restrict__ per_batch, float* __restrict__ out)
{
    const int lane = threadIdx.x;
    float v = per_batch[lane] + per_batch[lane + 64];
    #pragma unroll
    for (int off = 32; off > 0; off >>= 1) {
        v += __shfl_down(v, off, 64);
    }
    if (lane == 0) out[0] = v / (float)B_DIM;
}

extern "C" void kernel_launch(void* const* d_in, const int* in_sizes, int n_in,
                              void* d_out, int out_size, void* d_ws, size_t ws_size,
                              hipStream_t stream) {
    const float* log_probs = (const float*)d_in[0];
    const int* targets = (const int*)d_in[1];
    const int* target_lengths = (const int*)d_in[2];
    float* out = (float*)d_out;
    float* per_batch = (float*)d_ws;  // B_DIM floats of scratch

    ctc_alpha_kernel<<<B_DIM, 64, 0, stream>>>(log_probs, targets,
                                               target_lengths, per_batch);
    ctc_reduce_kernel<<<1, 64, 0, stream>>>(per_batch, out);
}

// Round 7
// 108.604 us; speedup vs baseline: 2.4285x; 1.0939x over previous
//
#include <hip/hip_runtime.h>
#include <math.h>

#define NEGINF (-1e30f)
#define LOG2E  1.4426950408889634f
#define LN2    0.6931471805599453f

// Problem constants (fixed by setup_inputs)
#define T_DIM 1024
#define B_DIM 128
#define C_DIM 256
#define S_DIM 64
#define L_DIM (2 * S_DIM + 1)  // 129
#define CH 16                  // timesteps per LDS-staged chunk
#define NCH (T_DIM / CH)       // 64 chunks

// lane i <- lane i-1; lane 0 <- NEGINF. wave_shr:1 DPP (gfx9 ctrl 0x138).
__device__ __forceinline__ float shfl_up1_neginf(float x) {
    int r = __builtin_amdgcn_update_dpp(__float_as_int(NEGINF),
                                        __float_as_int(x),
                                        0x138 /*WAVE_SHR1*/, 0xF, 0xF, false);
    return __int_as_float(r);
}

__device__ __forceinline__ float fexp2(float x) { return __builtin_amdgcn_exp2f(x); }
__device__ __forceinline__ float flog2(float x) { return __builtin_amdgcn_logf(x); }

// Async global->LDS, 4B per lane: per-lane global source address, wave-uniform
// LDS dest (lane i lands at lds + i*4). Tracked by vmcnt; the compiler cannot
// sink or soften this the way it did the round-6 register ring.
#define GLOAD_LDS4(gp, lp)                                                     \
    __builtin_amdgcn_global_load_lds(                                          \
        (const __attribute__((address_space(1))) void*)(gp),                   \
        (__attribute__((address_space(3))) void*)(lp), 4, 0, 0)

// One wave (64 lanes) per batch element. Lane l owns extended states
// s0=2l (blank), s1=2l+1 (label targets[b,l]); lane 63's a2 is state 128.
// Alpha in registers (log2 domain); cross-lane dep = one DPP per step.
// Log-probs arrive via LDS chunks staged with global_load_lds, double-buffered
// with counted vmcnt waits (never 0 in the main loop).
__global__ __launch_bounds__(64) void ctc_alpha_kernel(
    const float* __restrict__ log_probs,    // (T, B, C)
    const int* __restrict__ targets,        // (B, S)
    const int* __restrict__ target_lengths, // (B,)
    float* __restrict__ per_batch)          // (B,) loss_b / len_b
{
    const int b = blockIdx.x;
    const int lane = threadIdx.x;  // 0..63

    __shared__ float lbuf[2][CH][64];  // label-prob chunks (per-lane gather)
    __shared__ float bbuf[2][64];      // blank-prob chunks (slots 0..CH-1 used)
    __shared__ float als[L_DIM + 3];

    // Per-lane fixed label class and skip flag (constant over t).
    const int e1 = targets[b * S_DIM + lane];               // class of state 2l+1
    const int ep = (lane > 0) ? targets[b * S_DIM + lane - 1] : 0;
    const bool skip = (lane > 0) && (e1 != ep);

    const float* base = log_probs + (size_t)b * C_DIM;
    const size_t stride = (size_t)B_DIM * C_DIM;  // floats per timestep
    const float* glab = base + e1;                // per-lane label column

    // t = 0 init (log2 domain).
    float a0, a1, a2;
    {
        float r00 = base[0];        // lp[0,b,blank]
        float r0e = base[e1];       // lp[0,b,e1]
        a0 = (lane == 0) ? r00 * LOG2E : NEGINF;  // alpha[0]
        a1 = (lane == 0) ? r0e * LOG2E : NEGINF;  // alpha[1]
        a2 = NEGINF;                              // alpha[128]
    }

    // Issue one chunk's 17 loads (16 label gathers + 1 blank strip).
    // Chunk c covers timesteps t0..t0+CH-1, t0 = 1 + CH*c (clamped at T-1;
    // the clamped duplicate slot is never consumed).
#define ISSUE_CHUNK(C_, BUF_)                                                  \
    do {                                                                       \
        const int t0_ = 1 + CH * (C_);                                         \
        _Pragma("unroll")                                                      \
        for (int k_ = 0; k_ < CH; ++k_) {                                      \
            int t_ = t0_ + k_;                                                 \
            t_ = (t_ < T_DIM) ? t_ : (T_DIM - 1);                              \
            GLOAD_LDS4(glab + (size_t)t_ * stride, &lbuf[BUF_][k_][0]);        \
        }                                                                      \
        int tb_ = t0_ + (lane & (CH - 1));                                     \
        tb_ = (tb_ < T_DIM) ? tb_ : (T_DIM - 1);                               \
        GLOAD_LDS4(base + (size_t)tb_ * stride, &bbuf[BUF_][0]);               \
    } while (0)

    // One recursion step (log2 domain). 2-term LSEs use the
    // max + log2(1 + 2^-|d|) form (exp2's -abs input modifier is free).
#define CTC_STEP(LPB, LPL)                                                     \
    do {                                                                       \
        float lpb = (LPB) * LOG2E;                                             \
        float lpl = (LPL) * LOG2E;                                             \
        float am1 = shfl_up1_neginf(a1);              /* alpha[2l-1] */        \
        float d0 = a0 - am1;                                                   \
        float n0 = fmaxf(a0, am1) + flog2(1.0f + fexp2(-fabsf(d0))) + lpb;     \
        float s2v = skip ? am1 : NEGINF;                                       \
        float m1 = fmaxf(fmaxf(a1, a0), s2v);                                  \
        float n1 = m1 + flog2(fexp2(a1 - m1) + fexp2(a0 - m1) +                \
                              fexp2(s2v - m1)) + lpl;                          \
        float d2 = a2 - a1;                                                    \
        float n2 = fmaxf(a2, a1) + flog2(1.0f + fexp2(-fabsf(d2))) + lpb;      \
        a0 = n0; a1 = n1; a2 = n2;                                             \
    } while (0)

    // Prologue: chunk 0 in flight.
    ISSUE_CHUNK(0, 0);

    // Chunks 0..NCH-2 are full (16 steps each, t = 1..1008).
    for (int c = 0; c < NCH - 1; ++c) {
        ISSUE_CHUNK(c + 1, (c + 1) & 1);
        // 17 newer ops (chunk c+1) may remain in flight; chunk c has landed.
        asm volatile("s_waitcnt vmcnt(17)" ::: "memory");
        const int buf = c & 1;
        #pragma unroll
        for (int k = 0; k < CH; ++k) {
            float pl = lbuf[buf][k][lane];
            float pb = bbuf[buf][k];
            CTC_STEP(pb, pl);
        }
    }
    // Tail chunk (c = NCH-1, parity 1): 15 steps, t = 1009..1023.
    asm volatile("s_waitcnt vmcnt(0)" ::: "memory");
    #pragma unroll
    for (int k = 0; k < CH - 1; ++k) {
        float pl = lbuf[1][k][lane];
        float pb = bbuf[1][k];
        CTC_STEP(pb, pl);
    }
#undef CTC_STEP
#undef ISSUE_CHUNK

    // Publish final alpha (log2 domain) and compute per-batch loss.
    als[2 * lane] = a0;
    als[2 * lane + 1] = a1;
    if (lane == 63) als[L_DIM - 1] = a2;
    __syncthreads();

    if (lane == 0) {
        const int len = target_lengths[b];
        float aLast = als[2 * len];
        float aPrev = als[2 * len - 1];
        float m = fmaxf(aLast, aPrev);
        float la2 = m + flog2(fexp2(aLast - m) + fexp2(aPrev - m));
        float loss = -(la2 * LN2);
        if (!isfinite(loss) || !(loss < 1e29f)) loss = 0.0f;
        per_batch[b] = loss / (float)len;
    }
}

// Single-wave deterministic reduction: mean over B of per_batch.
__global__ __launch_bounds__(64) void ctc_reduce_kernel(
    const float* __restrict__ per_batch, float* __restrict__ out)
{
    const int lane = threadIdx.x;
    float v = per_batch[lane] + per_batch[lane + 64];
    #pragma unroll
    for (int off = 32; off > 0; off >>= 1) {
        v += __shfl_down(v, off, 64);
    }
    if (lane == 0) out[0] = v / (float)B_DIM;
}

extern "C" void kernel_launch(void* const* d_in, const int* in_sizes, int n_in,
                              void* d_out, int out_size, void* d_ws, size_t ws_size,
                              hipStream_t stream) {
    const float* log_probs = (const float*)d_in[0];
    const int* targets = (const int*)d_in[1];
    const int* target_lengths = (const int*)d_in[2];
    float* out = (float*)d_out;
    float* per_batch = (float*)d_ws;  // B_DIM floats of scratch

    ctc_alpha_kernel<<<B_DIM, 64, 0, stream>>>(log_probs, targets,
                                               target_lengths, per_batch);
    ctc_reduce_kernel<<<1, 64, 0, stream>>>(per_batch, out);
}

// Round 10
// 86.150 us; speedup vs baseline: 3.0614x; 1.2606x over previous
//
#include <hip/hip_runtime.h>
#include <math.h>

#define LOG2E  1.4426950408889634f
#define LN2    0.6931471805599453f

// Problem constants (fixed by setup_inputs)
#define T_DIM 1024
#define B_DIM 128
#define C_DIM 256
#define S_DIM 64
#define L_DIM (2 * S_DIM + 1)  // 129
#define CH 16                  // timesteps per LDS-staged chunk
#define NCH (T_DIM / CH)       // 64 chunks

__device__ __forceinline__ float fexp2(float x) { return __builtin_amdgcn_exp2f(x); }
__device__ __forceinline__ float flog2(float x) { return __builtin_amdgcn_logf(x); }

// lane i <- lane i-1; lane 0 <- 0. wave_shr:1 DPP (gfx9 ctrl 0x138).
__device__ __forceinline__ int dpp_shr1_i(int x) {
    return __builtin_amdgcn_update_dpp(0, x, 0x138 /*WAVE_SHR1*/, 0xF, 0xF, false);
}

// Async global->LDS, 4B/lane: per-lane global source, wave-uniform LDS dest
// (lane i lands at lds + 4*i). Tracked by vmcnt; compiler cannot sink it.
#define GLOAD_LDS4(gp, lp)                                                     \
    __builtin_amdgcn_global_load_lds(                                          \
        (const __attribute__((address_space(1))) void*)(gp),                   \
        (__attribute__((address_space(3))) void*)(lp), 4, 0, 0)

// One wave per batch element. Lane l owns extended states s0=2l (blank),
// s1=2l+1 (label targets[b,l]); lane 63's a2 is state 128.
// LINEAR-domain alpha with PER-LANE exponent el: true_alpha = a * 2^el.
// Cross-lane inflow (am1) is re-scaled by 2^(eprev-el); inactive lanes
// (all-zero states) adopt the neighbor's exponent each step so the first
// wavefront inflow lands exactly. No transcendentals on the recursion.
__global__ __launch_bounds__(64) void ctc_alpha_kernel(
    const float* __restrict__ log_probs,    // (T, B, C)
    const int* __restrict__ targets,        // (B, S)
    const int* __restrict__ target_lengths, // (B,)
    float* __restrict__ per_batch)          // (B,) loss_b / len_b
{
    const int b = blockIdx.x;
    const int lane = threadIdx.x;  // 0..63

    __shared__ float lbuf[3][CH][64];  // label-prob chunks (per-lane gather)
    __shared__ float bbuf[3][64];      // blank-prob strips (slots 0..CH-1 used)
    __shared__ float als[L_DIM + 3];

    const int e1 = targets[b * S_DIM + lane];               // class of state 2l+1
    const int ep = (lane > 0) ? targets[b * S_DIM + lane - 1] : 0;
    const bool skip = (lane > 0) && (e1 != ep);

    const float* base = log_probs + (size_t)b * C_DIM;
    const size_t stride = (size_t)B_DIM * C_DIM;  // floats per timestep
    const float* glab = base + e1;                // per-lane label column

    // t = 0 init (linear domain, scale el=0).
    float i0 = base[0];
    float ie = base[e1];
    float a0 = (lane == 0) ? fexp2(i0 * LOG2E) : 0.0f;  // alpha[0]
    float a1 = (lane == 0) ? fexp2(ie * LOG2E) : 0.0f;  // alpha[1]
    float a2 = 0.0f;                                    // alpha[128]
    int el = 0;  // per-lane: log2(true alpha) = log2(a) + el

    // Per-lane exact renorm: eb = exponent(max state); a *= 2^-eb; el += eb.
    // Power-of-two multiply is exact. mx==0 -> eb=-127, sc*0=0: harmless.
    // Between rescales (4 steps) shrink stays >> 2^-126, so mx is normal.
#define RESCALE()                                                              \
    do {                                                                       \
        float mx_ = fmaxf(a0, fmaxf(a1, a2));                                  \
        int eb_ = (int)((__float_as_uint(mx_) >> 23) & 0xFFu) - 127;           \
        el += eb_;                                                             \
        float sc_ = __uint_as_float((unsigned)(127 - eb_) << 23);              \
        a0 *= sc_; a1 *= sc_; a2 *= sc_;                                       \
    } while (0)

    // Issue one chunk's 17 loads (16 label gathers + 1 blank strip).
#define ISSUE_CHUNK(C_, BUF_)                                                  \
    do {                                                                       \
        const int t0_ = 1 + CH * (C_);                                         \
        _Pragma("unroll")                                                      \
        for (int k_ = 0; k_ < CH; ++k_) {                                      \
            int t_ = t0_ + k_;                                                 \
            t_ = (t_ < T_DIM) ? t_ : (T_DIM - 1);                              \
            GLOAD_LDS4(glab + (size_t)t_ * stride, &lbuf[BUF_][k_][0]);        \
        }                                                                      \
        int tb_ = t0_ + (lane & (CH - 1));                                     \
        tb_ = (tb_ < T_DIM) ? tb_ : (T_DIM - 1);                               \
        GLOAD_LDS4(base + (size_t)tb_ * stride, &bbuf[BUF_][0]);               \
    } while (0)

    // Compute N_ steps from buffer BUF_: batch all LDS reads into registers
    // (one lgkmcnt window, pinned by sched_barrier), then pure-VALU recursion.
#define COMPUTE_CHUNK(BUF_, N_)                                                \
    do {                                                                       \
        float plr_[CH], pbr_[CH];                                              \
        _Pragma("unroll")                                                      \
        for (int k_ = 0; k_ < CH; ++k_) {                                      \
            plr_[k_] = lbuf[BUF_][k_][lane];                                   \
            pbr_[k_] = bbuf[BUF_][k_];                                         \
        }                                                                      \
        __builtin_amdgcn_sched_barrier(0);                                     \
        _Pragma("unroll")                                                      \
        for (int k_ = 0; k_ < (N_); ++k_) {                                    \
            float pbv_ = fexp2(pbr_[k_] * LOG2E);                              \
            float plv_ = fexp2(plr_[k_] * LOG2E);                              \
            float am1_ = __int_as_float(dpp_shr1_i(__float_as_int(a1)));       \
            int eprev_ = dpp_shr1_i(el);                                       \
            int iz_ = __float_as_int(a0) | __float_as_int(a1) |                \
                      __float_as_int(a2);                                      \
            int ele_ = (iz_ == 0) ? eprev_ : el;   /* adopt scale if virgin */ \
            float am1s_ = ldexpf(am1_, eprev_ - ele_);                         \
            el = ele_;                                                         \
            float n0_ = (a0 + am1s_) * pbv_;                                   \
            float s2_ = skip ? am1s_ : 0.0f;                                   \
            float n1_ = (a1 + a0 + s2_) * plv_;                                \
            float n2_ = (a2 + a1) * pbv_;                                      \
            a0 = n0_; a1 = n1_; a2 = n2_;                                      \
            if ((k_ & 3) == 3) RESCALE();                                      \
        }                                                                      \
    } while (0)

    // Triple-buffered pipeline: 2 chunks in flight during compute.
    ISSUE_CHUNK(0, 0);
    ISSUE_CHUNK(1, 1);
    for (int c = 0; c < NCH - 2; ++c) {
        ISSUE_CHUNK(c + 2, (c + 2) % 3);
        // 34 newer ops (2 chunks) may remain in flight; chunk c has landed.
        asm volatile("s_waitcnt vmcnt(34)" ::: "memory");
        COMPUTE_CHUNK(c % 3, CH);
    }
    asm volatile("s_waitcnt vmcnt(17)" ::: "memory");
    COMPUTE_CHUNK((NCH - 2) % 3, CH);      // chunk 62, buffer 2
    asm volatile("s_waitcnt vmcnt(0)" ::: "memory");
    COMPUTE_CHUNK((NCH - 1) % 3, CH - 1);  // chunk 63, buffer 0, 15 steps

#undef COMPUTE_CHUNK
#undef ISSUE_CHUNK
#undef RESCALE

    // Publish final alpha as log2 values (restores full dynamic range).
    als[2 * lane] = flog2(a0) + (float)el;
    als[2 * lane + 1] = flog2(a1) + (float)el;
    if (lane == 63) als[L_DIM - 1] = flog2(a2) + (float)el;
    __syncthreads();

    if (lane == 0) {
        const int len = target_lengths[b];
        float x = als[2 * len];
        float y = als[2 * len - 1];
        float mx = fmaxf(x, y);
        float lse2 = mx + flog2(1.0f + fexp2(-fabsf(x - y)));  // log2-domain
        float loss = -(lse2 * LN2);
        if (!isfinite(loss) || !(loss < 1e29f)) loss = 0.0f;
        per_batch[b] = loss / (float)len;
    }
}

// Single-wave deterministic reduction: mean over B of per_batch.
__global__ __launch_bounds__(64) void ctc_reduce_kernel(
    const float* __restrict__ per_batch, float* __restrict__ out)
{
    const int lane = threadIdx.x;
    float v = per_batch[lane] + per_batch[lane + 64];
    #pragma unroll
    for (int off = 32; off > 0; off >>= 1) {
        v += __shfl_down(v, off, 64);
    }
    if (lane == 0) out[0] = v / (float)B_DIM;
}

extern "C" void kernel_launch(void* const* d_in, const int* in_sizes, int n_in,
                              void* d_out, int out_size, void* d_ws, size_t ws_size,
                              hipStream_t stream) {
    const float* log_probs = (const float*)d_in[0];
    const int* targets = (const int*)d_in[1];
    const int* target_lengths = (const int*)d_in[2];
    float* out = (float*)d_out;
    float* per_batch = (float*)d_ws;  // B_DIM floats of scratch

    ctc_alpha_kernel<<<B_DIM, 64, 0, stream>>>(log_probs, targets,
                                               target_lengths, per_batch);
    ctc_reduce_kernel<<<1, 64, 0, stream>>>(per_batch, out);
}

// Round 12
// 81.890 us; speedup vs baseline: 3.2207x; 1.0520x over previous
//
#include <hip/hip_runtime.h>
#include <math.h>

#define LOG2E  1.4426950408889634f
#define LN2    0.6931471805599453f

// Problem constants (fixed by setup_inputs)
#define T_DIM 1024
#define B_DIM 128
#define C_DIM 256
#define S_DIM 64
#define L_DIM (2 * S_DIM + 1)  // 129
#define CH 16                  // timesteps per LDS-staged chunk
#define NCH (T_DIM / CH)       // 64 chunks

__device__ __forceinline__ float fexp2(float x) { return __builtin_amdgcn_exp2f(x); }
__device__ __forceinline__ float flog2(float x) { return __builtin_amdgcn_logf(x); }

// lane i <- lane i-1; lane 0 <- 0. wave_shr:1 DPP (gfx9 ctrl 0x138).
__device__ __forceinline__ int dpp_shr1_i(int x) {
    return __builtin_amdgcn_update_dpp(0, x, 0x138 /*WAVE_SHR1*/, 0xF, 0xF, false);
}

// Async global->LDS, 16B per lane: fully-coalesced row stage (lane i reads
// row+16*i, lands at lds+16*i). One op stages a whole 1KiB class row.
#define GLOAD_LDS16(gp, lp)                                                    \
    __builtin_amdgcn_global_load_lds(                                          \
        (const __attribute__((address_space(1))) void*)(gp),                   \
        (__attribute__((address_space(3))) void*)(lp), 16, 0, 0)

// One wave per batch element. Lane l owns extended states s0=2l (blank),
// s1=2l+1 (label targets[b,l]); lane 63's a2 is state 128.
// LINEAR-domain alpha with PER-LANE exponent el: true_alpha = a * 2^el.
// Full class rows are staged to LDS coalesced (16 coalesced ops/chunk
// instead of 17 divergent gathers); the per-class gather happens in LDS.
__global__ __launch_bounds__(64) void ctc_alpha_kernel(
    const float* __restrict__ log_probs,    // (T, B, C)
    const int* __restrict__ targets,        // (B, S)
    const int* __restrict__ target_lengths, // (B,)
    float* __restrict__ per_batch)          // (B,) loss_b / len_b
{
    const int b = blockIdx.x;
    const int lane = threadIdx.x;  // 0..63

    __shared__ float rbuf[3][CH][C_DIM];  // staged class rows (1KiB each)
    __shared__ float als[L_DIM + 3];

    const int e1 = targets[b * S_DIM + lane];               // class of state 2l+1
    const int ep = (lane > 0) ? targets[b * S_DIM + lane - 1] : 0;
    const bool skip = (lane > 0) && (e1 != ep);

    const float* base = log_probs + (size_t)b * C_DIM;
    const size_t stride = (size_t)B_DIM * C_DIM;  // floats per timestep

    // t = 0 init (linear domain, scale el=0).
    float i0 = base[0];
    float ie = base[e1];
    float a0 = (lane == 0) ? fexp2(i0 * LOG2E) : 0.0f;  // alpha[0]
    float a1 = (lane == 0) ? fexp2(ie * LOG2E) : 0.0f;  // alpha[1]
    float a2 = 0.0f;                                    // alpha[128]
    int el = 0;  // per-lane: log2(true alpha) = log2(a) + el

    // Per-lane exact renorm: eb = exponent(max state); a *= 2^-eb; el += eb.
#define RESCALE()                                                              \
    do {                                                                       \
        float mx_ = fmaxf(a0, fmaxf(a1, a2));                                  \
        int eb_ = (int)((__float_as_uint(mx_) >> 23) & 0xFFu) - 127;           \
        el += eb_;                                                             \
        float sc_ = __uint_as_float((unsigned)(127 - eb_) << 23);              \
        a0 *= sc_; a1 *= sc_; a2 *= sc_;                                       \
    } while (0)

    // Issue one chunk's 16 coalesced row stages (timesteps t0..t0+15,
    // clamped at T-1; clamped duplicate slots are never consumed).
#define ISSUE_CHUNK(C_, BUF_)                                                  \
    do {                                                                       \
        const int t0_ = 1 + CH * (C_);                                         \
        _Pragma("unroll")                                                      \
        for (int k_ = 0; k_ < CH; ++k_) {                                      \
            int t_ = t0_ + k_;                                                 \
            t_ = (t_ < T_DIM) ? t_ : (T_DIM - 1);                              \
            GLOAD_LDS16(base + (size_t)t_ * stride, &rbuf[BUF_][k_][0]);       \
        }                                                                      \
    } while (0)

    // Compute N_ steps from buffer BUF_: batch the LDS gathers into registers
    // (one lgkmcnt window; label read ~2-way bank alias = free, blank is a
    // broadcast), then pure-VALU linear recursion.
#define COMPUTE_CHUNK(BUF_, N_)                                                \
    do {                                                                       \
        float plr_[CH], pbr_[CH];                                              \
        _Pragma("unroll")                                                      \
        for (int k_ = 0; k_ < CH; ++k_) {                                      \
            plr_[k_] = rbuf[BUF_][k_][e1];                                     \
            pbr_[k_] = rbuf[BUF_][k_][0];                                      \
        }                                                                      \
        __builtin_amdgcn_sched_barrier(0);                                     \
        _Pragma("unroll")                                                      \
        for (int k_ = 0; k_ < (N_); ++k_) {                                    \
            float pbv_ = fexp2(pbr_[k_] * LOG2E);                              \
            float plv_ = fexp2(plr_[k_] * LOG2E);                              \
            float am1_ = __int_as_float(dpp_shr1_i(__float_as_int(a1)));       \
            int eprev_ = dpp_shr1_i(el);                                       \
            int iz_ = __float_as_int(a0) | __float_as_int(a1) |                \
                      __float_as_int(a2);                                      \
            int ele_ = (iz_ == 0) ? eprev_ : el;   /* adopt scale if virgin */ \
            float am1s_ = ldexpf(am1_, eprev_ - ele_);                         \
            el = ele_;                                                         \
            float n0_ = (a0 + am1s_) * pbv_;                                   \
            float s2_ = skip ? am1s_ : 0.0f;                                   \
            float n1_ = (a1 + a0 + s2_) * plv_;                                \
            float n2_ = (a2 + a1) * pbv_;                                      \
            a0 = n0_; a1 = n1_; a2 = n2_;                                      \
            if ((k_ & 3) == 3) RESCALE();                                      \
        }                                                                      \
    } while (0)

    // Triple-buffered pipeline: 2 chunks (32 coalesced ops) in flight.
    ISSUE_CHUNK(0, 0);
    ISSUE_CHUNK(1, 1);
    for (int c = 0; c < NCH - 2; ++c) {
        ISSUE_CHUNK(c + 2, (c + 2) % 3);
        // 32 newer ops (2 chunks) may remain in flight; chunk c has landed.
        asm volatile("s_waitcnt vmcnt(32)" ::: "memory");
        COMPUTE_CHUNK(c % 3, CH);
    }
    asm volatile("s_waitcnt vmcnt(16)" ::: "memory");
    COMPUTE_CHUNK((NCH - 2) % 3, CH);      // chunk 62, buffer 2
    asm volatile("s_waitcnt vmcnt(0)" ::: "memory");
    COMPUTE_CHUNK((NCH - 1) % 3, CH - 1);  // chunk 63, buffer 0, 15 steps

#undef COMPUTE_CHUNK
#undef ISSUE_CHUNK
#undef RESCALE

    // Publish final alpha as log2 values (restores full dynamic range).
    als[2 * lane] = flog2(a0) + (float)el;
    als[2 * lane + 1] = flog2(a1) + (float)el;
    if (lane == 63) als[L_DIM - 1] = flog2(a2) + (float)el;
    __syncthreads();

    if (lane == 0) {
        const int len = target_lengths[b];
        float x = als[2 * len];
        float y = als[2 * len - 1];
        float mx = fmaxf(x, y);
        float lse2 = mx + flog2(1.0f + fexp2(-fabsf(x - y)));  // log2-domain
        float loss = -(lse2 * LN2);
        if (!isfinite(loss) || !(loss < 1e29f)) loss = 0.0f;
        per_batch[b] = loss / (float)len;
    }
}

// Single-wave deterministic reduction: mean over B of per_batch.
__global__ __launch_bounds__(64) void ctc_reduce_kernel(
    const float* __restrict__ per_batch, float* __restrict__ out)
{
    const int lane = threadIdx.x;
    float v = per_batch[lane] + per_batch[lane + 64];
    #pragma unroll
    for (int off = 32; off > 0; off >>= 1) {
        v += __shfl_down(v, off, 64);
    }
    if (lane == 0) out[0] = v / (float)B_DIM;
}

extern "C" void kernel_launch(void* const* d_in, const int* in_sizes, int n_in,
                              void* d_out, int out_size, void* d_ws, size_t ws_size,
                              hipStream_t stream) {
    const float* log_probs = (const float*)d_in[0];
    const int* targets = (const int*)d_in[1];
    const int* target_lengths = (const int*)d_in[2];
    float* out = (float*)d_out;
    float* per_batch = (float*)d_ws;  // B_DIM floats of scratch

    ctc_alpha_kernel<<<B_DIM, 64, 0, stream>>>(log_probs, targets,
                                               target_lengths, per_batch);
    ctc_reduce_kernel<<<1, 64, 0, stream>>>(per_batch, out);
}

// Round 13
// 75.965 us; speedup vs baseline: 3.4719x; 1.0780x over previous
//
#include <hip/hip_runtime.h>
#include <math.h>

#define LOG2E  1.4426950408889634f
#define LN2    0.6931471805599453f

// Problem constants (fixed by setup_inputs)
#define T_DIM 1024
#define B_DIM 128
#define C_DIM 256
#define S_DIM 64
#define L_DIM (2 * S_DIM + 1)  // 129
#define CH 16                  // timesteps per LDS-staged chunk
#define NCH (T_DIM / CH)       // 64 chunks

__device__ __forceinline__ float fexp2(float x) { return __builtin_amdgcn_exp2f(x); }
__device__ __forceinline__ float flog2(float x) { return __builtin_amdgcn_logf(x); }

// lane i <- lane i-1; lane 0 <- 0. wave_shr:1 DPP (gfx9 ctrl 0x138).
__device__ __forceinline__ int dpp_shr1_i(int x) {
    return __builtin_amdgcn_update_dpp(0, x, 0x138 /*WAVE_SHR1*/, 0xF, 0xF, false);
}

// Async global->LDS, 16B per lane. GLOBAL SOURCE IS PER-LANE: caller must
// pass gp such that lane i's pointer is row_base + 16*i bytes (we add
// 4*lane floats). LDS dest is wave-uniform; HW writes lds + 16*lane.
#define GLOAD_LDS16(gp, lp)                                                    \
    __builtin_amdgcn_global_load_lds(                                          \
        (const __attribute__((address_space(1))) void*)(gp),                   \
        (__attribute__((address_space(3))) void*)(lp), 16, 0, 0)

#define VMWAIT(N_) asm volatile("s_waitcnt vmcnt(" #N_ ")" ::: "memory")

// One wave per batch element. Lane l owns extended states s0=2l (blank),
// s1=2l+1 (label targets[b,l]); lane 63's a2 is state 128.
// LINEAR-domain alpha with PER-LANE exponent el: true_alpha = a * 2^el.
// Full class rows staged to LDS coalesced (16B/lane), 4-buffer ring,
// quarter-granular counted vmcnt waits; per-class gather via ds_read.
__global__ __launch_bounds__(64) void ctc_alpha_kernel(
    const float* __restrict__ log_probs,    // (T, B, C)
    const int* __restrict__ targets,        // (B, S)
    const int* __restrict__ target_lengths, // (B,)
    float* __restrict__ per_batch)          // (B,) loss_b / len_b
{
    const int b = blockIdx.x;
    const int lane = threadIdx.x;  // 0..63

    __shared__ float rbuf[4][CH][C_DIM];  // staged class rows (1KiB each)
    __shared__ float als[L_DIM + 3];

    const int e1 = targets[b * S_DIM + lane];               // class of state 2l+1
    const int ep = (lane > 0) ? targets[b * S_DIM + lane - 1] : 0;
    const bool skip = (lane > 0) && (e1 != ep);

    const float* base = log_probs + (size_t)b * C_DIM;
    const size_t stride = (size_t)B_DIM * C_DIM;  // floats per timestep

    // t = 0 init (linear domain, scale el=0).
    float i0 = base[0];
    float ie = base[e1];
    float a0 = (lane == 0) ? fexp2(i0 * LOG2E) : 0.0f;  // alpha[0]
    float a1 = (lane == 0) ? fexp2(ie * LOG2E) : 0.0f;  // alpha[1]
    float a2 = 0.0f;                                    // alpha[128]
    int el = 0;    // per-lane: log2(true alpha) = log2(a) + el
    int dexp = 0;  // eprev - el, constant within a 4-step rescale window

    // Per-lane exact renorm: eb = exponent(max state); a *= 2^-eb; el += eb.
#define RESCALE()                                                              \
    do {                                                                       \
        float mx_ = fmaxf(a0, fmaxf(a1, a2));                                  \
        int eb_ = (int)((__float_as_uint(mx_) >> 23) & 0xFFu) - 127;           \
        el += eb_;                                                             \
        float sc_ = __uint_as_float((unsigned)(127 - eb_) << 23);              \
        a0 *= sc_; a1 *= sc_; a2 *= sc_;                                       \
    } while (0)

    // Issue one chunk: 16 coalesced row stages, per-lane source 16B/lane.
#define ISSUE_CHUNK(C_, BUF_)                                                  \
    do {                                                                       \
        const int t0_ = 1 + CH * (C_);                                         \
        _Pragma("unroll")                                                      \
        for (int k_ = 0; k_ < CH; ++k_) {                                      \
            int t_ = t0_ + k_;                                                 \
            t_ = (t_ < T_DIM) ? t_ : (T_DIM - 1);                              \
            GLOAD_LDS16(base + (size_t)t_ * stride + 4 * lane,                 \
                        &rbuf[BUF_][k_][0]);                                   \
        }                                                                      \
    } while (0)

    // Activation-phase step (first 9 chunks): full virgin-adopt logic.
#define ACT_STEP(LPB, LPL, K_)                                                 \
    do {                                                                       \
        float pbv_ = fexp2((LPB) * LOG2E);                                     \
        float plv_ = fexp2((LPL) * LOG2E);                                     \
        float am1_ = __int_as_float(dpp_shr1_i(__float_as_int(a1)));           \
        int eprev_ = dpp_shr1_i(el);                                           \
        int iz_ = __float_as_int(a0) | __float_as_int(a1) |                    \
                  __float_as_int(a2);                                          \
        int ele_ = (iz_ == 0) ? eprev_ : el;                                   \
        float am1s_ = ldexpf(am1_, eprev_ - ele_);                             \
        el = ele_;                                                             \
        float n0_ = (a0 + am1s_) * pbv_;                                       \
        float s2_ = skip ? am1s_ : 0.0f;                                       \
        float n1_ = (a1 + a0 + s2_) * plv_;                                    \
        float n2_ = (a2 + a1) * pbv_;                                          \
        a0 = n0_; a1 = n1_; a2 = n2_;                                          \
        if (((K_) & 3) == 3) RESCALE();                                        \
    } while (0)

    // Steady-state step: el/eprev constant within the window -> dexp reused.
#define STREAM_STEP(LPB, LPL)                                                  \
    do {                                                                       \
        float pbv_ = fexp2((LPB) * LOG2E);                                     \
        float plv_ = fexp2((LPL) * LOG2E);                                     \
        float am1_ = __int_as_float(dpp_shr1_i(__float_as_int(a1)));           \
        float am1s_ = ldexpf(am1_, dexp);                                      \
        float n0_ = (a0 + am1s_) * pbv_;                                       \
        float s2_ = skip ? am1s_ : 0.0f;                                       \
        float n1_ = (a1 + a0 + s2_) * plv_;                                    \
        float n2_ = (a2 + a1) * pbv_;                                          \
        a0 = n0_; a1 = n1_; a2 = n2_;                                          \
    } while (0)

    // Whole-chunk activation compute (wait = all 16 rows landed).
#define ACT_CHUNK(BUF_)                                                        \
    do {                                                                       \
        VMWAIT(48);                                                            \
        float plr_[CH], pbr_[CH];                                              \
        _Pragma("unroll")                                                      \
        for (int k_ = 0; k_ < CH; ++k_) {                                      \
            plr_[k_] = rbuf[BUF_][k_][e1];                                     \
            pbr_[k_] = rbuf[BUF_][k_][0];                                      \
        }                                                                      \
        __builtin_amdgcn_sched_barrier(0);                                     \
        _Pragma("unroll")                                                      \
        for (int k_ = 0; k_ < CH; ++k_) {                                      \
            ACT_STEP(pbr_[k_], plr_[k_], k_);                                  \
        }                                                                      \
    } while (0)

    // One steady-state quarter: wait 4 rows, gather, 4 steps, rescale.
#define STREAM_QUARTER(BUF_, Q_, W_)                                           \
    do {                                                                       \
        VMWAIT(W_);                                                            \
        float pl0_ = rbuf[BUF_][4 * (Q_) + 0][e1];                             \
        float pb0_ = rbuf[BUF_][4 * (Q_) + 0][0];                              \
        float pl1_ = rbuf[BUF_][4 * (Q_) + 1][e1];                             \
        float pb1_ = rbuf[BUF_][4 * (Q_) + 1][0];                              \
        float pl2_ = rbuf[BUF_][4 * (Q_) + 2][e1];                             \
        float pb2_ = rbuf[BUF_][4 * (Q_) + 2][0];                              \
        float pl3_ = rbuf[BUF_][4 * (Q_) + 3][e1];                             \
        float pb3_ = rbuf[BUF_][4 * (Q_) + 3][0];                              \
        __builtin_amdgcn_sched_barrier(0);                                     \
        dexp = dpp_shr1_i(el) - el;                                            \
        STREAM_STEP(pb0_, pl0_);                                               \
        STREAM_STEP(pb1_, pl1_);                                               \
        STREAM_STEP(pb2_, pl2_);                                               \
        STREAM_STEP(pb3_, pl3_);                                               \
        RESCALE();                                                             \
    } while (0)

#define STREAM_CHUNK(BUF_, W0_, W1_, W2_, W3_)                                 \
    do {                                                                       \
        STREAM_QUARTER(BUF_, 0, W0_);                                          \
        STREAM_QUARTER(BUF_, 1, W1_);                                          \
        STREAM_QUARTER(BUF_, 2, W2_);                                          \
        STREAM_QUARTER(BUF_, 3, W3_);                                          \
    } while (0)

    // 4-buffer ring, 3 chunks ahead in flight.
    ISSUE_CHUNK(0, 0);
    ISSUE_CHUNK(1, 1);
    ISSUE_CHUNK(2, 2);
    // Activation chunks 0..8 (t = 1..144; all lanes active by t~70).
    for (int c = 0; c < 9; ++c) {
        ISSUE_CHUNK(c + 3, (c + 3) & 3);
        ACT_CHUNK(c & 3);
    }
    // Steady-state chunks 9..60 (still issuing).
    for (int c = 9; c < 61; ++c) {
        ISSUE_CHUNK(c + 3, (c + 3) & 3);
        STREAM_CHUNK(c & 3, 60, 56, 52, 48);
    }
    // Drain: chunks 61, 62 (full), 63 (15 steps).
    STREAM_CHUNK(1, 44, 40, 36, 32);
    STREAM_CHUNK(2, 28, 24, 20, 16);
    {
        STREAM_QUARTER(3, 0, 12);
        STREAM_QUARTER(3, 1, 8);
        STREAM_QUARTER(3, 2, 4);
        VMWAIT(0);
        float pl0_ = rbuf[3][12][e1], pb0_ = rbuf[3][12][0];
        float pl1_ = rbuf[3][13][e1], pb1_ = rbuf[3][13][0];
        float pl2_ = rbuf[3][14][e1], pb2_ = rbuf[3][14][0];
        __builtin_amdgcn_sched_barrier(0);
        dexp = dpp_shr1_i(el) - el;
        STREAM_STEP(pb0_, pl0_);
        STREAM_STEP(pb1_, pl1_);
        STREAM_STEP(pb2_, pl2_);
    }

#undef STREAM_CHUNK
#undef STREAM_QUARTER
#undef ACT_CHUNK
#undef STREAM_STEP
#undef ACT_STEP
#undef ISSUE_CHUNK
#undef RESCALE

    // Publish final alpha as log2 values (restores full dynamic range).
    als[2 * lane] = flog2(a0) + (float)el;
    als[2 * lane + 1] = flog2(a1) + (float)el;
    if (lane == 63) als[L_DIM - 1] = flog2(a2) + (float)el;
    __syncthreads();

    if (lane == 0) {
        const int len = target_lengths[b];
        float x = als[2 * len];
        float y = als[2 * len - 1];
        float mx = fmaxf(x, y);
        float lse2 = mx + flog2(1.0f + fexp2(-fabsf(x - y)));  // log2-domain
        float loss = -(lse2 * LN2);
        if (!isfinite(loss) || !(loss < 1e29f)) loss = 0.0f;
        per_batch[b] = loss / (float)len;
    }
}

// Single-wave deterministic reduction: mean over B of per_batch.
__global__ __launch_bounds__(64) void ctc_reduce_kernel(
    const float* __restrict__ per_batch, float* __restrict__ out)
{
    const int lane = threadIdx.x;
    float v = per_batch[lane] + per_batch[lane + 64];
    #pragma unroll
    for (int off = 32; off > 0; off >>= 1) {
        v += __shfl_down(v, off, 64);
    }
    if (lane == 0) out[0] = v / (float)B_DIM;
}

extern "C" void kernel_launch(void* const* d_in, const int* in_sizes, int n_in,
                              void* d_out, int out_size, void* d_ws, size_t ws_size,
                              hipStream_t stream) {
    const float* log_probs = (const float*)d_in[0];
    const int* targets = (const int*)d_in[1];
    const int* target_lengths = (const int*)d_in[2];
    float* out = (float*)d_out;
    float* per_batch = (float*)d_ws;  // B_DIM floats of scratch

    ctc_alpha_kernel<<<B_DIM, 64, 0, stream>>>(log_probs, targets,
                                               target_lengths, per_batch);
    ctc_reduce_kernel<<<1, 64, 0, stream>>>(per_batch, out);
}

// Round 14
// 68.501 us; speedup vs baseline: 3.8502x; 1.1090x over previous
//
#include <hip/hip_runtime.h>
#include <math.h>

#define LOG2E  1.4426950408889634f
#define LN2    0.6931471805599453f

// Problem constants (fixed by setup_inputs)
#define T_DIM 1024
#define B_DIM 128
#define C_DIM 256
#define S_DIM 64
#define L_DIM (2 * S_DIM + 1)  // 129
#define CH 16                  // timesteps per LDS-staged chunk
#define NCH (T_DIM / CH)       // 64 chunks

__device__ __forceinline__ float fexp2(float x) { return __builtin_amdgcn_exp2f(x); }
__device__ __forceinline__ float flog2(float x) { return __builtin_amdgcn_logf(x); }

// lane i <- lane i-1; lane 0 <- 0. wave_shr:1 DPP (gfx9 ctrl 0x138).
__device__ __forceinline__ int dpp_shr1_i(int x) {
    return __builtin_amdgcn_update_dpp(0, x, 0x138 /*WAVE_SHR1*/, 0xF, 0xF, false);
}

// Async global->LDS, 16B per lane. Global source is PER-LANE (row_base +
// 16B*lane); LDS dest wave-uniform (HW writes lds + 16B*lane).
#define GLOAD_LDS16(gp, lp)                                                    \
    __builtin_amdgcn_global_load_lds(                                          \
        (const __attribute__((address_space(1))) void*)(gp),                   \
        (__attribute__((address_space(3))) void*)(lp), 16, 0, 0)

#define VMWAIT(N_) asm volatile("s_waitcnt vmcnt(" #N_ ")" ::: "memory")

// PRODUCER/CONSUMER: 2 waves per block (one block per batch element).
// Wave 1 stages full class rows to LDS (coalesced global_load_lds, 3 chunks
// ahead, owns ALL vmcnt waits). Wave 0 runs the recursion with zero VMEM:
// per chunk, barrier -> batched ds_read gather -> 16 pure-VALU steps.
// Alpha: LINEAR domain with per-lane exponent el (true_alpha = a * 2^el).
__global__ __launch_bounds__(128) void ctc_alpha_kernel(
    const float* __restrict__ log_probs,    // (T, B, C)
    const int* __restrict__ targets,        // (B, S)
    const int* __restrict__ target_lengths, // (B,)
    float* __restrict__ per_batch)          // (B,) loss_b / len_b
{
    const int b = blockIdx.x;
    const int tid = threadIdx.x;
    const int lane = tid & 63;
    const int wid = tid >> 6;   // 0 = consumer, 1 = producer

    __shared__ float rbuf[4][CH][C_DIM];  // 64 KB: staged class rows

    const int e1 = targets[b * S_DIM + lane];               // class of state 2l+1
    const int ep = (lane > 0) ? targets[b * S_DIM + lane - 1] : 0;
    const bool skip = (lane > 0) && (e1 != ep);

    const float* base = log_probs + (size_t)b * C_DIM;
    const size_t stride = (size_t)B_DIM * C_DIM;  // floats per timestep

    // t = 0 init (linear domain, scale el=0) — consumer wave state.
    float i0 = base[0];
    float ie = base[e1];
    float a0 = (lane == 0) ? fexp2(i0 * LOG2E) : 0.0f;  // alpha[0]
    float a1 = (lane == 0) ? fexp2(ie * LOG2E) : 0.0f;  // alpha[1]
    float a2 = 0.0f;                                    // alpha[128]
    int el = 0;    // per-lane: log2(true alpha) = log2(a) + el
    int dexp = 0;  // eprev - el, constant within a 4-step rescale window

#define RESCALE()                                                              \
    do {                                                                       \
        float mx_ = fmaxf(a0, fmaxf(a1, a2));                                  \
        int eb_ = (int)((__float_as_uint(mx_) >> 23) & 0xFFu) - 127;           \
        el += eb_;                                                             \
        float sc_ = __uint_as_float((unsigned)(127 - eb_) << 23);              \
        a0 *= sc_; a1 *= sc_; a2 *= sc_;                                       \
    } while (0)

    // Producer: one chunk = 16 coalesced row stages (per-lane src 16B/lane).
#define ISSUE_CHUNK(C_, BUF_)                                                  \
    do {                                                                       \
        const int t0_ = 1 + CH * (C_);                                         \
        _Pragma("unroll")                                                      \
        for (int k_ = 0; k_ < CH; ++k_) {                                      \
            int t_ = t0_ + k_;                                                 \
            t_ = (t_ < T_DIM) ? t_ : (T_DIM - 1);                              \
            GLOAD_LDS16(base + (size_t)t_ * stride + 4 * lane,                 \
                        &rbuf[BUF_][k_][0]);                                   \
        }                                                                      \
    } while (0)

    // Activation-phase step (first 9 chunks): full virgin-adopt logic.
#define ACT_STEP(LPB, LPL, K_)                                                 \
    do {                                                                       \
        float pbv_ = fexp2((LPB) * LOG2E);                                     \
        float plv_ = fexp2((LPL) * LOG2E);                                     \
        float am1_ = __int_as_float(dpp_shr1_i(__float_as_int(a1)));           \
        int eprev_ = dpp_shr1_i(el);                                           \
        int iz_ = __float_as_int(a0) | __float_as_int(a1) |                    \
                  __float_as_int(a2);                                          \
        int ele_ = (iz_ == 0) ? eprev_ : el;                                   \
        float am1s_ = ldexpf(am1_, eprev_ - ele_);                             \
        el = ele_;                                                             \
        float n0_ = (a0 + am1s_) * pbv_;                                       \
        float s2_ = skip ? am1s_ : 0.0f;                                       \
        float n1_ = (a1 + a0 + s2_) * plv_;                                    \
        float n2_ = (a2 + a1) * pbv_;                                          \
        a0 = n0_; a1 = n1_; a2 = n2_;                                          \
        if (((K_) & 3) == 3) RESCALE();                                        \
    } while (0)

    // Steady-state step: el/eprev constant within the window -> dexp reused.
#define STREAM_STEP(LPB, LPL)                                                  \
    do {                                                                       \
        float pbv_ = fexp2((LPB) * LOG2E);                                     \
        float plv_ = fexp2((LPL) * LOG2E);                                     \
        float am1_ = __int_as_float(dpp_shr1_i(__float_as_int(a1)));           \
        float am1s_ = ldexpf(am1_, dexp);                                      \
        float n0_ = (a0 + am1s_) * pbv_;                                       \
        float s2_ = skip ? am1s_ : 0.0f;                                       \
        float n1_ = (a1 + a0 + s2_) * plv_;                                    \
        float n2_ = (a2 + a1) * pbv_;                                          \
        a0 = n0_; a1 = n1_; a2 = n2_;                                          \
    } while (0)

    // Consumer chunk bodies: batch-gather 32 LDS values, then compute.
#define GATHER(BUF_)                                                           \
    float plr_[CH], pbr_[CH];                                                  \
    _Pragma("unroll")                                                          \
    for (int k_ = 0; k_ < CH; ++k_) {                                          \
        plr_[k_] = rbuf[BUF_][k_][e1];                                         \
        pbr_[k_] = rbuf[BUF_][k_][0];                                          \
    }                                                                          \
    __builtin_amdgcn_sched_barrier(0)

#define ACT_CHUNK(BUF_)                                                        \
    do {                                                                       \
        GATHER(BUF_);                                                          \
        _Pragma("unroll")                                                      \
        for (int k_ = 0; k_ < CH; ++k_) {                                      \
            ACT_STEP(pbr_[k_], plr_[k_], k_);                                  \
        }                                                                      \
    } while (0)

#define STREAM_CHUNK(BUF_)                                                     \
    do {                                                                       \
        GATHER(BUF_);                                                          \
        _Pragma("unroll")                                                      \
        for (int q_ = 0; q_ < 4; ++q_) {                                       \
            dexp = dpp_shr1_i(el) - el;                                        \
            STREAM_STEP(pbr_[4 * q_ + 0], plr_[4 * q_ + 0]);                   \
            STREAM_STEP(pbr_[4 * q_ + 1], plr_[4 * q_ + 1]);                   \
            STREAM_STEP(pbr_[4 * q_ + 2], plr_[4 * q_ + 2]);                   \
            STREAM_STEP(pbr_[4 * q_ + 3], plr_[4 * q_ + 3]);                   \
            RESCALE();                                                         \
        }                                                                      \
    } while (0)

#define TAIL_CHUNK(BUF_)                                                       \
    do {                                                                       \
        GATHER(BUF_);                                                          \
        _Pragma("unroll")                                                      \
        for (int q_ = 0; q_ < 3; ++q_) {                                       \
            dexp = dpp_shr1_i(el) - el;                                        \
            STREAM_STEP(pbr_[4 * q_ + 0], plr_[4 * q_ + 0]);                   \
            STREAM_STEP(pbr_[4 * q_ + 1], plr_[4 * q_ + 1]);                   \
            STREAM_STEP(pbr_[4 * q_ + 2], plr_[4 * q_ + 2]);                   \
            STREAM_STEP(pbr_[4 * q_ + 3], plr_[4 * q_ + 3]);                   \
            RESCALE();                                                         \
        }                                                                      \
        dexp = dpp_shr1_i(el) - el;                                            \
        STREAM_STEP(pbr_[12], plr_[12]);                                       \
        STREAM_STEP(pbr_[13], plr_[13]);                                       \
        STREAM_STEP(pbr_[14], plr_[14]);                                       \
    } while (0)

    // Producer prologue: 3 chunks in flight.
    if (wid == 1) {
        ISSUE_CHUNK(0, 0);
        ISSUE_CHUNK(1, 1);
        ISSUE_CHUNK(2, 2);
    }

    for (int c = 0; c < NCH; ++c) {
        if (wid == 1) {
            // Guarantee chunk c's 16 ops have landed (LDS writes done).
            if (c < NCH - 2)      VMWAIT(32);
            else if (c == NCH - 2) VMWAIT(16);
            else                   VMWAIT(0);
        }
        __syncthreads();  // buf c%4 visible to consumer
        if (wid == 0) {
            if (c < 9)            ACT_CHUNK(c & 3);
            else if (c < NCH - 1) STREAM_CHUNK(c & 3);
            else                  TAIL_CHUNK(c & 3);
        }
        __syncthreads();  // consumer done with buf c%4
        if (wid == 1 && c + 3 < NCH) {
            ISSUE_CHUNK(c + 3, (c + 3) & 3);  // reuse the freed buffer
        }
    }

#undef TAIL_CHUNK
#undef STREAM_CHUNK
#undef ACT_CHUNK
#undef GATHER
#undef STREAM_STEP
#undef ACT_STEP
#undef ISSUE_CHUNK
#undef RESCALE

    // Terminal (consumer wave only): states 2*len and 2*len-1 via uniform-
    // index shuffles (no LDS, no cross-wave sync needed).
    if (wid == 0) {
        const int len = target_lengths[b];
        float la0 = flog2(a0) + (float)el;
        float la1 = flog2(a1) + (float)el;
        float la2 = flog2(a2) + (float)el;
        float x = (len == S_DIM) ? __shfl(la2, 63, 64) : __shfl(la0, len, 64);
        float y = __shfl(la1, len - 1, 64);
        if (lane == 0) {
            float mx = fmaxf(x, y);
            float lse2 = mx + flog2(1.0f + fexp2(-fabsf(x - y)));
            float loss = -(lse2 * LN2);
            if (!isfinite(loss) || !(loss < 1e29f)) loss = 0.0f;
            per_batch[b] = loss / (float)len;
        }
    }
}

// Single-wave deterministic reduction: mean over B of per_batch.
__global__ __launch_bounds__(64) void ctc_reduce_kernel(
    const float* __restrict__ per_batch, float* __restrict__ out)
{
    const int lane = threadIdx.x;
    float v = per_batch[lane] + per_batch[lane + 64];
    #pragma unroll
    for (int off = 32; off > 0; off >>= 1) {
        v += __shfl_down(v, off, 64);
    }
    if (lane == 0) out[0] = v / (float)B_DIM;
}

extern "C" void kernel_launch(void* const* d_in, const int* in_sizes, int n_in,
                              void* d_out, int out_size, void* d_ws, size_t ws_size,
                              hipStream_t stream) {
    const float* log_probs = (const float*)d_in[0];
    const int* targets = (const int*)d_in[1];
    const int* target_lengths = (const int*)d_in[2];
    float* out = (float*)d_out;
    float* per_batch = (float*)d_ws;  // B_DIM floats of scratch

    ctc_alpha_kernel<<<B_DIM, 128, 0, stream>>>(log_probs, targets,
                                                target_lengths, per_batch);
    ctc_reduce_kernel<<<1, 64, 0, stream>>>(per_batch, out);
}

// Round 15
// 58.550 us; speedup vs baseline: 4.5045x; 1.1700x over previous
//
#include <hip/hip_runtime.h>
#include <math.h>

#define LOG2E  1.4426950408889634f
#define LN2    0.6931471805599453f

// Problem constants (fixed by setup_inputs)
#define T_DIM 1024
#define B_DIM 128
#define C_DIM 256
#define S_DIM 64
#define L_DIM (2 * S_DIM + 1)  // 129
#define CH 16                  // timesteps per LDS-staged chunk
#define NCH (T_DIM / CH)       // 64 chunks
#define NBUF 6                 // LDS buffer ring depth (96 KB)

__device__ __forceinline__ float fexp2(float x) { return __builtin_amdgcn_exp2f(x); }
__device__ __forceinline__ float flog2(float x) { return __builtin_amdgcn_logf(x); }

// lane i <- lane i-1; lane 0 <- 0. wave_shr:1 DPP (gfx9 ctrl 0x138).
__device__ __forceinline__ int dpp_shr1_i(int x) {
    return __builtin_amdgcn_update_dpp(0, x, 0x138 /*WAVE_SHR1*/, 0xF, 0xF, false);
}

// Async global->LDS, 16B per lane. Global source is PER-LANE (row_base +
// 16B*lane); LDS dest wave-uniform (HW writes lds + 16B*lane).
#define GLOAD_LDS16(gp, lp)                                                    \
    __builtin_amdgcn_global_load_lds(                                          \
        (const __attribute__((address_space(1))) void*)(gp),                   \
        (__attribute__((address_space(3))) void*)(lp), 16, 0, 0)

#define VMWAIT(N_) asm volatile("s_waitcnt vmcnt(" #N_ ")" ::: "memory")

// PRODUCER/CONSUMER with LDS-flag handshake (no per-chunk barriers).
// Wave 1 stages class rows (coalesced global_load_lds, 6-buffer ring,
// owns all vmcnt waits, publishes landed-chunk count in prodf). Wave 0
// runs the recursion with zero VMEM and zero barriers: poll prodf,
// gather from LDS, 16 pure-VALU steps, bump consf.
// Alpha: LINEAR domain with per-lane exponent el (true_alpha = a * 2^el).
__global__ __launch_bounds__(128) void ctc_alpha_kernel(
    const float* __restrict__ log_probs,    // (T, B, C)
    const int* __restrict__ targets,        // (B, S)
    const int* __restrict__ target_lengths, // (B,)
    float* __restrict__ per_batch)          // (B,) loss_b / len_b
{
    const int b = blockIdx.x;
    const int tid = threadIdx.x;
    const int lane = tid & 63;
    const int wid = tid >> 6;   // 0 = consumer, 1 = producer

    __shared__ float rbuf[NBUF][CH][C_DIM];  // 96 KB staged class rows
    __shared__ int prodf;  // # chunks fully landed in LDS
    __shared__ int consf;  // # chunks fully consumed

    const int e1 = targets[b * S_DIM + lane];               // class of state 2l+1
    const int ep = (lane > 0) ? targets[b * S_DIM + lane - 1] : 0;
    const bool skip = (lane > 0) && (e1 != ep);

    const float* base = log_probs + (size_t)b * C_DIM;
    const size_t stride = (size_t)B_DIM * C_DIM;  // floats per timestep

    // t = 0 init (linear domain, scale el=0) — consumer wave state.
    float i0 = base[0];
    float ie = base[e1];
    float a0 = (lane == 0) ? fexp2(i0 * LOG2E) : 0.0f;  // alpha[0]
    float a1 = (lane == 0) ? fexp2(ie * LOG2E) : 0.0f;  // alpha[1]
    float a2 = 0.0f;                                    // alpha[128]
    int el = 0;    // per-lane: log2(true alpha) = log2(a) + el
    int dexp = 0;  // eprev - el, constant within a 4-step rescale window

    if (tid == 0) { prodf = 0; consf = 0; }
    __syncthreads();  // the only barrier in the kernel

#define RESCALE()                                                              \
    do {                                                                       \
        float mx_ = fmaxf(a0, fmaxf(a1, a2));                                  \
        int eb_ = (int)((__float_as_uint(mx_) >> 23) & 0xFFu) - 127;           \
        el += eb_;                                                             \
        float sc_ = __uint_as_float((unsigned)(127 - eb_) << 23);              \
        a0 *= sc_; a1 *= sc_; a2 *= sc_;                                       \
    } while (0)

#define ISSUE_CHUNK(C_, BUF_)                                                  \
    do {                                                                       \
        const int t0_ = 1 + CH * (C_);                                         \
        _Pragma("unroll")                                                      \
        for (int k_ = 0; k_ < CH; ++k_) {                                      \
            int t_ = t0_ + k_;                                                 \
            t_ = (t_ < T_DIM) ? t_ : (T_DIM - 1);                              \
            GLOAD_LDS16(base + (size_t)t_ * stride + 4 * lane,                 \
                        &rbuf[BUF_][k_][0]);                                   \
        }                                                                      \
    } while (0)

    // Activation-phase step (first 9 chunks): full virgin-adopt logic.
#define ACT_STEP(LPB, LPL, K_)                                                 \
    do {                                                                       \
        float pbv_ = fexp2((LPB) * LOG2E);                                     \
        float plv_ = fexp2((LPL) * LOG2E);                                     \
        float am1_ = __int_as_float(dpp_shr1_i(__float_as_int(a1)));           \
        int eprev_ = dpp_shr1_i(el);                                           \
        int iz_ = __float_as_int(a0) | __float_as_int(a1) |                    \
                  __float_as_int(a2);                                          \
        int ele_ = (iz_ == 0) ? eprev_ : el;                                   \
        float am1s_ = ldexpf(am1_, eprev_ - ele_);                             \
        el = ele_;                                                             \
        float n0_ = (a0 + am1s_) * pbv_;                                       \
        float s2_ = skip ? am1s_ : 0.0f;                                       \
        float n1_ = (a1 + a0 + s2_) * plv_;                                    \
        float n2_ = (a2 + a1) * pbv_;                                          \
        a0 = n0_; a1 = n1_; a2 = n2_;                                          \
        if (((K_) & 3) == 3) RESCALE();                                        \
    } while (0)

    // Steady-state step: el/eprev constant within the window -> dexp reused.
#define STREAM_STEP(LPB, LPL)                                                  \
    do {                                                                       \
        float pbv_ = fexp2((LPB) * LOG2E);                                     \
        float plv_ = fexp2((LPL) * LOG2E);                                     \
        float am1_ = __int_as_float(dpp_shr1_i(__float_as_int(a1)));           \
        float am1s_ = ldexpf(am1_, dexp);                                      \
        float n0_ = (a0 + am1s_) * pbv_;                                       \
        float s2_ = skip ? am1s_ : 0.0f;                                       \
        float n1_ = (a1 + a0 + s2_) * plv_;                                    \
        float n2_ = (a2 + a1) * pbv_;                                          \
        a0 = n0_; a1 = n1_; a2 = n2_;                                          \
    } while (0)

#define GATHER(BUF_)                                                           \
    float plr_[CH], pbr_[CH];                                                  \
    _Pragma("unroll")                                                          \
    for (int k_ = 0; k_ < CH; ++k_) {                                          \
        plr_[k_] = rbuf[BUF_][k_][e1];                                         \
        pbr_[k_] = rbuf[BUF_][k_][0];                                          \
    }                                                                          \
    __builtin_amdgcn_sched_barrier(0)

#define ACT_CHUNK(BUF_)                                                        \
    do {                                                                       \
        GATHER(BUF_);                                                          \
        _Pragma("unroll")                                                      \
        for (int k_ = 0; k_ < CH; ++k_) {                                      \
            ACT_STEP(pbr_[k_], plr_[k_], k_);                                  \
        }                                                                      \
    } while (0)

#define STREAM_CHUNK(BUF_)                                                     \
    do {                                                                       \
        GATHER(BUF_);                                                          \
        _Pragma("unroll")                                                      \
        for (int q_ = 0; q_ < 4; ++q_) {                                       \
            dexp = dpp_shr1_i(el) - el;                                        \
            STREAM_STEP(pbr_[4 * q_ + 0], plr_[4 * q_ + 0]);                   \
            STREAM_STEP(pbr_[4 * q_ + 1], plr_[4 * q_ + 1]);                   \
            STREAM_STEP(pbr_[4 * q_ + 2], plr_[4 * q_ + 2]);                   \
            STREAM_STEP(pbr_[4 * q_ + 3], plr_[4 * q_ + 3]);                   \
            RESCALE();                                                         \
        }                                                                      \
    } while (0)

#define TAIL_CHUNK(BUF_)                                                       \
    do {                                                                       \
        GATHER(BUF_);                                                          \
        _Pragma("unroll")                                                      \
        for (int q_ = 0; q_ < 3; ++q_) {                                       \
            dexp = dpp_shr1_i(el) - el;                                        \
            STREAM_STEP(pbr_[4 * q_ + 0], plr_[4 * q_ + 0]);                   \
            STREAM_STEP(pbr_[4 * q_ + 1], plr_[4 * q_ + 1]);                   \
            STREAM_STEP(pbr_[4 * q_ + 2], plr_[4 * q_ + 2]);                   \
            STREAM_STEP(pbr_[4 * q_ + 3], plr_[4 * q_ + 3]);                   \
            RESCALE();                                                         \
        }                                                                      \
        dexp = dpp_shr1_i(el) - el;                                            \
        STREAM_STEP(pbr_[12], plr_[12]);                                       \
        STREAM_STEP(pbr_[13], plr_[13]);                                       \
        STREAM_STEP(pbr_[14], plr_[14]);                                       \
    } while (0)

    if (wid == 1) {
        // PRODUCER: free-running stager.
        volatile int* pf = &prodf;
        volatile int* cf = &consf;
        for (int c = 0; c < NCH; ++c) {
            if (c >= NBUF) {
                // buffer c%NBUF reused; consumer must be done with c-NBUF
                while (*cf < c - NBUF + 1) __builtin_amdgcn_s_sleep(1);
            }
            ISSUE_CHUNK(c, c % NBUF);
            VMWAIT(32);  // chunks <= c-2 have fully landed
            __builtin_amdgcn_sched_barrier(0);
            if (c >= 2 && lane == 0) *pf = c - 1;
        }
        VMWAIT(16);
        __builtin_amdgcn_sched_barrier(0);
        if (lane == 0) *pf = NCH - 1;
        VMWAIT(0);
        __builtin_amdgcn_sched_barrier(0);
        if (lane == 0) *pf = NCH;
    } else {
        // CONSUMER: zero VMEM, zero barriers.
        volatile int* pf = &prodf;
        volatile int* cf = &consf;
        for (int c = 0; c < NCH; ++c) {
            while (*pf < c + 1) { /* producer is normally ahead */ }
            __builtin_amdgcn_sched_barrier(0);
            asm volatile("" ::: "memory");  // pin data reads after flag read
            if (c < 9)            ACT_CHUNK(c % NBUF);
            else if (c < NCH - 1) STREAM_CHUNK(c % NBUF);
            else                  TAIL_CHUNK(c % NBUF);
            if (lane == 0) *cf = c + 1;
        }
    }

#undef TAIL_CHUNK
#undef STREAM_CHUNK
#undef ACT_CHUNK
#undef GATHER
#undef STREAM_STEP
#undef ACT_STEP
#undef ISSUE_CHUNK
#undef RESCALE

    // Terminal (consumer wave): states 2*len and 2*len-1 via uniform shuffles.
    if (wid == 0) {
        const int len = target_lengths[b];
        float la0 = flog2(a0) + (float)el;
        float la1 = flog2(a1) + (float)el;
        float la2 = flog2(a2) + (float)el;
        float x = (len == S_DIM) ? __shfl(la2, 63, 64) : __shfl(la0, len, 64);
        float y = __shfl(la1, len - 1, 64);
        if (lane == 0) {
            float mx = fmaxf(x, y);
            float lse2 = mx + flog2(1.0f + fexp2(-fabsf(x - y)));
            float loss = -(lse2 * LN2);
            if (!isfinite(loss) || !(loss < 1e29f)) loss = 0.0f;
            per_batch[b] = loss / (float)len;
        }
    }
}

// Single-wave deterministic reduction: mean over B of per_batch.
__global__ __launch_bounds__(64) void ctc_reduce_kernel(
    const float* __restrict__ per_batch, float* __restrict__ out)
{
    const int lane = threadIdx.x;
    float v = per_batch[lane] + per_batch[lane + 64];
    #pragma unroll
    for (int off = 32; off > 0; off >>= 1) {
        v += __shfl_down(v, off, 64);
    }
    if (lane == 0) out[0] = v / (float)B_DIM;
}

extern "C" void kernel_launch(void* const* d_in, const int* in_sizes, int n_in,
                              void* d_out, int out_size, void* d_ws, size_t ws_size,
                              hipStream_t stream) {
    const float* log_probs = (const float*)d_in[0];
    const int* targets = (const int*)d_in[1];
    const int* target_lengths = (const int*)d_in[2];
    float* out = (float*)d_out;
    float* per_batch = (float*)d_ws;  // B_DIM floats of scratch

    ctc_alpha_kernel<<<B_DIM, 128, 0, stream>>>(log_probs, targets,
                                                target_lengths, per_batch);
    ctc_reduce_kernel<<<1, 64, 0, stream>>>(per_batch, out);
}